// Round 4
// baseline (926.102 us; speedup 1.0000x reference)
//
#include <hip/hip_runtime.h>
#include <stdint.h>
#include <math.h>

typedef unsigned short u16;
typedef __attribute__((ext_vector_type(8))) short s16x8;
typedef __attribute__((ext_vector_type(4))) short s16x4;
typedef __attribute__((ext_vector_type(4))) float f32x4;

__device__ __forceinline__ float bf2f(u16 v) {
  union { unsigned u; float f; } c; c.u = ((unsigned)v) << 16; return c.f;
}
__device__ __forceinline__ u16 f2bf(float f) {
  union { float f; unsigned u; } c; c.f = f;
  unsigned u = c.u;
  u += 0x7fffu + ((u >> 16) & 1u);   // round-to-nearest-even
  return (u16)(u >> 16);
}

#define GLD_LDS16(g, l) __builtin_amdgcn_global_load_lds( \
    (const __attribute__((address_space(1))) void*)(g),   \
    (__attribute__((address_space(3))) void*)(l), 16, 0, 0)

// ---------------------------------------------------------------------------
// GEMM: C[M,N] = A[M,K] * B[N,K]^T + bias[N].
// ABF=true: A is bf16 ws buffer (global_load_lds path).
// ABF=false: A is f32 input, cvt->bf16 at staging.
// B: f32 input weight, cvt->bf16 at staging. bias f32. fp32 accum.
// EPI: 0 = write bf16, 1 = write f32, 2 = mish -> bf16
// ---------------------------------------------------------------------------
template<bool ABF, int EPI>
__global__ __launch_bounds__(256) void gemm_bt(
    const void* __restrict__ Av, const float* __restrict__ B,
    const float* __restrict__ bias, void* __restrict__ Cv,
    int M, int N, int K)
{
  __shared__ __align__(16) u16 As[128*32];
  __shared__ __align__(16) u16 Bs[128*32];
  const int tid = threadIdx.x;
  const int lane = tid & 63;
  const int wave = tid >> 6;
  const int wr = wave >> 1, wc = wave & 1;
  const int l15 = lane & 15, kg = lane >> 4;
  const long bm = (long)blockIdx.y * 128, bn = (long)blockIdx.x * 128;

  f32x4 acc[4][4] = {};

  for (int k0 = 0; k0 < K; k0 += 32) {
    if (ABF) {
      const u16* A = (const u16*)Av;
#pragma unroll
      for (int i = 0; i < 2; ++i) {
        const int e = (i*256 + tid) * 8;
        const int row = e >> 5, col = e & 31;
        GLD_LDS16(A + (bm + row) * (long)K + k0 + col, (char*)As + (i*4 + wave)*1024);
      }
    } else {
      const float* A = (const float*)Av;
#pragma unroll
      for (int p = 0; p < 4; ++p) {
        const int idx = p*256 + tid;
        const int row = idx >> 3, c4 = (idx & 7) * 4;
        float4 f = *(const float4*)&A[(bm + row) * (long)K + k0 + c4];
        s16x4 h;
        h[0] = (short)f2bf(f.x); h[1] = (short)f2bf(f.y);
        h[2] = (short)f2bf(f.z); h[3] = (short)f2bf(f.w);
        *(s16x4*)&As[row*32 + c4] = h;
      }
    }
#pragma unroll
    for (int p = 0; p < 4; ++p) {
      const int idx = p*256 + tid;
      const int row = idx >> 3, c4 = (idx & 7) * 4;
      float4 f = *(const float4*)&B[(bn + row) * (long)K + k0 + c4];
      s16x4 h;
      h[0] = (short)f2bf(f.x); h[1] = (short)f2bf(f.y);
      h[2] = (short)f2bf(f.z); h[3] = (short)f2bf(f.w);
      *(s16x4*)&Bs[row*32 + c4] = h;
    }
    __syncthreads();
    s16x8 a[4], b[4];
#pragma unroll
    for (int mi = 0; mi < 4; ++mi)
      a[mi] = *(const s16x8*)&As[(wr*64 + mi*16 + l15)*32 + kg*8];
#pragma unroll
    for (int ni = 0; ni < 4; ++ni)
      b[ni] = *(const s16x8*)&Bs[(wc*64 + ni*16 + l15)*32 + kg*8];
#pragma unroll
    for (int mi = 0; mi < 4; ++mi)
#pragma unroll
      for (int ni = 0; ni < 4; ++ni)
        acc[mi][ni] = __builtin_amdgcn_mfma_f32_16x16x32_bf16(a[mi], b[ni], acc[mi][ni], 0, 0, 0);
    __syncthreads();
  }

#pragma unroll
  for (int mi = 0; mi < 4; ++mi) {
#pragma unroll
    for (int ni = 0; ni < 4; ++ni) {
      const long col = bn + wc*64 + ni*16 + l15;
      const float bvv = bias[col];
#pragma unroll
      for (int r = 0; r < 4; ++r) {
        const long row = bm + wr*64 + mi*16 + kg*4 + r;
        float v = acc[mi][ni][r] + bvv;
        if (EPI == 0) {
          ((u16*)Cv)[row * N + col] = f2bf(v);
        } else if (EPI == 1) {
          ((float*)Cv)[row * N + col] = v;
        } else {
          float sp = (v > 20.f) ? v : log1pf(expf(v));
          ((u16*)Cv)[row * N + col] = f2bf(v * tanhf(sp));
        }
      }
    }
  }
}

// ---------------------------------------------------------------------------
// Per-head RMSNorm in place on bf16 ws buffer. One wave per (row, head).
// ---------------------------------------------------------------------------
__global__ __launch_bounds__(256) void rmsnorm_head(u16* __restrict__ q,
                                                    const float* __restrict__ w)
{
  const int gid = blockIdx.x * 4 + (threadIdx.x >> 6);
  const int lane = threadIdx.x & 63;
  const size_t idx = (size_t)(gid >> 4) * 1024 + (size_t)(gid & 15) * 64 + lane;
  float v = bf2f(q[idx]);
  float ss = v * v;
#pragma unroll
  for (int off = 32; off; off >>= 1) ss += __shfl_xor(ss, off);
  const float rms = sqrtf(ss * (1.0f/64.0f) + 1e-6f);
  q[idx] = f2bf(v / rms * w[lane]);
}

// ---------------------------------------------------------------------------
// Flash attention with additive f32 bias. Block = (q-tile 64, head, batch),
// 4 waves; each wave owns 16 q rows. hd = 64, KV tiles of 64.
// q/k/v bf16 (ws). scale 0.125 folded into Q at load (exact pow2).
// ---------------------------------------------------------------------------
__global__ __launch_bounds__(256) void attn_kernel(
    const u16* __restrict__ q, const u16* __restrict__ k, const u16* __restrict__ v,
    const float* __restrict__ bias, u16* __restrict__ out)
{
  const int T = 1024, Dm = 1024, H = 16;
  const int q0 = blockIdx.x * 64;
  const int h  = blockIdx.y;
  const int b  = blockIdx.z;
  __shared__ __align__(16) u16 Qs[64*64];
  __shared__ __align__(16) u16 Ks[64*64];
  __shared__ __align__(16) u16 Vt[64*64];
  __shared__ __align__(16) u16 Ps[64*64];
  __shared__ __align__(16) float Bstf[64*64];
  const int tid = threadIdx.x, lane = tid & 63, wave = tid >> 6;
  const int l15 = lane & 15, kg = lane >> 4;

#pragma unroll
  for (int i = 0; i < 2; ++i) {
    const int e = (i*256 + tid) * 8;
    const int r = e >> 6, d0 = e & 63;
    s16x8 v8 = *(const s16x8*)&q[(size_t)(b*T + q0 + r) * Dm + h*64 + d0];
#pragma unroll
    for (int j = 0; j < 8; ++j)
      Qs[r*64 + d0 + j] = f2bf(bf2f((u16)v8[j]) * 0.125f);
  }

  f32x4 accO[4] = {};
  float m_i[4], l_i[4];
#pragma unroll
  for (int r = 0; r < 4; ++r) { m_i[r] = -1e30f; l_i[r] = 0.f; }

  for (int kv0 = 0; kv0 < T; kv0 += 64) {
    __syncthreads();
#pragma unroll
    for (int i = 0; i < 2; ++i) {
      const int e = (i*256 + tid) * 8;
      const int r = e >> 6, d0 = e & 63;
      s16x8 k8 = *(const s16x8*)&k[(size_t)(b*T + kv0 + r) * Dm + h*64 + d0];
      *(s16x8*)&Ks[r*64 + d0] = k8;
      s16x8 v8 = *(const s16x8*)&v[(size_t)(b*T + kv0 + r) * Dm + h*64 + d0];
#pragma unroll
      for (int j = 0; j < 8; ++j) Vt[(d0 + j)*64 + r] = (u16)v8[j];
    }
    const size_t bias_base = ((size_t)(b*H + h)*T + q0) * T + kv0;  // + r*T + c
#pragma unroll
    for (int p = 0; p < 4; ++p) {
      const int idx = p*256 + tid;
      const int r = idx >> 4, c4 = (idx & 15) * 4;
      float4 b4 = *(const float4*)&bias[bias_base + (size_t)r*T + c4];
      *(float4*)&Bstf[r*64 + c4] = b4;
    }
    __syncthreads();

    f32x4 s[4] = {};
#pragma unroll
    for (int kc = 0; kc < 64; kc += 32) {
      s16x8 aq = *(const s16x8*)&Qs[(wave*16 + l15)*64 + kc + kg*8];
#pragma unroll
      for (int ni = 0; ni < 4; ++ni) {
        s16x8 bk = *(const s16x8*)&Ks[(ni*16 + l15)*64 + kc + kg*8];
        s[ni] = __builtin_amdgcn_mfma_f32_16x16x32_bf16(aq, bk, s[ni], 0, 0, 0);
      }
    }
    float pmax[4] = {-1e30f, -1e30f, -1e30f, -1e30f};
#pragma unroll
    for (int ni = 0; ni < 4; ++ni)
#pragma unroll
      for (int r = 0; r < 4; ++r) {
        float sv = s[ni][r] + Bstf[(wave*16 + kg*4 + r)*64 + ni*16 + l15];
        s[ni][r] = sv;
        pmax[r] = fmaxf(pmax[r], sv);
      }
#pragma unroll
    for (int r = 0; r < 4; ++r) {
#pragma unroll
      for (int off = 1; off < 16; off <<= 1)
        pmax[r] = fmaxf(pmax[r], __shfl_xor(pmax[r], off));
    }
    float alpha[4];
#pragma unroll
    for (int r = 0; r < 4; ++r) {
      const float mn = fmaxf(m_i[r], pmax[r]);
      alpha[r] = __expf(m_i[r] - mn);
      m_i[r] = mn;
    }
    float psum[4] = {0.f, 0.f, 0.f, 0.f};
#pragma unroll
    for (int ni = 0; ni < 4; ++ni)
#pragma unroll
      for (int r = 0; r < 4; ++r) {
        const float p = __expf(s[ni][r] - m_i[r]);
        psum[r] += p;
        Ps[(wave*16 + kg*4 + r)*64 + ni*16 + l15] = f2bf(p);
      }
#pragma unroll
    for (int r = 0; r < 4; ++r) {
#pragma unroll
      for (int off = 1; off < 16; off <<= 1)
        psum[r] += __shfl_xor(psum[r], off);
      l_i[r] = l_i[r] * alpha[r] + psum[r];
    }
#pragma unroll
    for (int nd = 0; nd < 4; ++nd)
#pragma unroll
      for (int r = 0; r < 4; ++r)
        accO[nd][r] *= alpha[r];
#pragma unroll
    for (int kc = 0; kc < 64; kc += 32) {
      s16x8 ap = *(const s16x8*)&Ps[(wave*16 + l15)*64 + kc + kg*8];
#pragma unroll
      for (int nd = 0; nd < 4; ++nd) {
        s16x8 bv = *(const s16x8*)&Vt[(nd*16 + l15)*64 + kc + kg*8];
        accO[nd] = __builtin_amdgcn_mfma_f32_16x16x32_bf16(ap, bv, accO[nd], 0, 0, 0);
      }
    }
  }

#pragma unroll
  for (int nd = 0; nd < 4; ++nd)
#pragma unroll
    for (int r = 0; r < 4; ++r) {
      const int row = q0 + wave*16 + kg*4 + r;
      const int col = h*64 + nd*16 + l15;
      out[(size_t)(b*T + row) * Dm + col] = f2bf(accO[nd][r] / l_i[r]);
    }
}

// ---------------------------------------------------------------------------
// LayerNorm(xa_f32 + xb_f32) * w + b.  One block per row, D=1024.
// MODE 0: write f32 outf AND bf16 outb.  MODE 1: write f32 outf only.
// ---------------------------------------------------------------------------
template<int MODE>
__global__ __launch_bounds__(256) void ln_kernel(
    const float* __restrict__ xa, const float* __restrict__ xb,
    const float* __restrict__ w, const float* __restrict__ bvec,
    float* __restrict__ outf, u16* __restrict__ outb)
{
  __shared__ float red[2][4];
  const int row = blockIdx.x;
  const int tid = threadIdx.x;
  const long base = (long)row * 1024 + tid*4;

  float4 xv = *(const float4*)&xa[base];
  float4 bv4 = *(const float4*)&xb[base];
  float vals[4];
  vals[0] = xv.x + bv4.x;
  vals[1] = xv.y + bv4.y;
  vals[2] = xv.z + bv4.z;
  vals[3] = xv.w + bv4.w;
  float s = 0.f, sq = 0.f;
#pragma unroll
  for (int j = 0; j < 4; ++j) { s += vals[j]; sq += vals[j]*vals[j]; }
#pragma unroll
  for (int off = 32; off; off >>= 1) {
    s  += __shfl_xor(s, off);
    sq += __shfl_xor(sq, off);
  }
  const int wv = tid >> 6;
  if ((tid & 63) == 0) { red[0][wv] = s; red[1][wv] = sq; }
  __syncthreads();
  const float st  = red[0][0] + red[0][1] + red[0][2] + red[0][3];
  const float sqt = red[1][0] + red[1][1] + red[1][2] + red[1][3];
  const float mu  = st * (1.f/1024.f);
  const float var = sqt * (1.f/1024.f) - mu*mu;
  const float rstd = rsqrtf(var + 1e-5f);
  if (MODE == 0) {
    float4 of;
    of.x = (vals[0] - mu) * rstd * w[tid*4+0] + bvec[tid*4+0];
    of.y = (vals[1] - mu) * rstd * w[tid*4+1] + bvec[tid*4+1];
    of.z = (vals[2] - mu) * rstd * w[tid*4+2] + bvec[tid*4+2];
    of.w = (vals[3] - mu) * rstd * w[tid*4+3] + bvec[tid*4+3];
    *(float4*)&outf[base] = of;
    s16x4 hb4;
    hb4[0] = (short)f2bf(of.x); hb4[1] = (short)f2bf(of.y);
    hb4[2] = (short)f2bf(of.z); hb4[3] = (short)f2bf(of.w);
    *(s16x4*)&outb[base] = hb4;
  } else {
    float4 of;
    of.x = (vals[0] - mu) * rstd * w[tid*4+0] + bvec[tid*4+0];
    of.y = (vals[1] - mu) * rstd * w[tid*4+1] + bvec[tid*4+1];
    of.z = (vals[2] - mu) * rstd * w[tid*4+2] + bvec[tid*4+2];
    of.w = (vals[3] - mu) * rstd * w[tid*4+3] + bvec[tid*4+3];
    *(float4*)&outf[base] = of;
  }
}

// ---------------------------------------------------------------------------
extern "C" void kernel_launch(void* const* d_in, const int* in_sizes, int n_in,
                              void* d_out, int out_size, void* d_ws, size_t ws_size,
                              hipStream_t stream)
{
  (void)in_sizes; (void)n_in; (void)out_size; (void)ws_size;
  const float* x    = (const float*)d_in[0];
  const float* sg   = (const float*)d_in[1];
  const float* Wq   = (const float*)d_in[2];
  const float* bq   = (const float*)d_in[3];
  const float* Wk   = (const float*)d_in[4];
  const float* bk   = (const float*)d_in[5];
  const float* Wv   = (const float*)d_in[6];
  const float* bv   = (const float*)d_in[7];
  const float* Wo   = (const float*)d_in[8];
  const float* bo   = (const float*)d_in[9];
  const float* qn   = (const float*)d_in[10];
  const float* kn   = (const float*)d_in[11];
  const float* ln1w = (const float*)d_in[12];
  const float* ln1b = (const float*)d_in[13];
  const float* W1   = (const float*)d_in[14];
  const float* b1   = (const float*)d_in[15];
  const float* W2   = (const float*)d_in[16];
  const float* b2   = (const float*)d_in[17];
  const float* ln2w = (const float*)d_in[18];
  const float* ln2b = (const float*)d_in[19];

  char* ws = (char*)d_ws;
  u16*   qb  = (u16*)(ws + (0ll   << 20));  // 16 MB bf16
  u16*   kb  = (u16*)(ws + (16ll  << 20));  // 16 MB bf16
  u16*   vb  = (u16*)(ws + (32ll  << 20));  // 16 MB bf16
  u16*   ao  = (u16*)(ws + (48ll  << 20));  // 16 MB bf16
  float* fb  = (float*)(ws + (64ll << 20)); // 32 MB f32 proj out
  float* x1f = (float*)(ws + (96ll << 20)); // 32 MB f32 post-LN1
  u16*   x1b = (u16*)(ws + (128ll << 20));  // 16 MB bf16 post-LN1
  u16*   hb  = (u16*)(ws + (0ll   << 20));  // 32 MB bf16 hidden (reuses qb+kb)
  float* fb2 = (float*)(ws + (32ll << 20)); // 32 MB f32 ffn2 out (reuses vb+ao)
  // high water: 144 MB (same as round 2, which ran correctly)

  const dim3 blk(256);

  // QKV projections (A = x f32, B = W f32)
  gemm_bt<false,0><<<dim3(8, 64), blk, 0, stream>>>(x, Wq, bq, qb, 8192, 1024, 1024);
  gemm_bt<false,0><<<dim3(8, 64), blk, 0, stream>>>(x, Wk, bk, kb, 8192, 1024, 1024);
  gemm_bt<false,0><<<dim3(8, 64), blk, 0, stream>>>(x, Wv, bv, vb, 8192, 1024, 1024);

  // per-head RMSNorm on q, k
  rmsnorm_head<<<32768, blk, 0, stream>>>(qb, qn);
  rmsnorm_head<<<32768, blk, 0, stream>>>(kb, kn);

  // attention with smolgen bias (f32)
  attn_kernel<<<dim3(16, 16, 8), blk, 0, stream>>>(qb, kb, vb, sg, ao);

  // output projection (A = ao bf16) -> f32
  gemm_bt<true,1><<<dim3(8, 64), blk, 0, stream>>>(ao, Wo, bo, fb, 8192, 1024, 1024);

  // LN1(x + proj) -> x1f (f32) + x1b (bf16)
  ln_kernel<0><<<8192, blk, 0, stream>>>(x, fb, ln1w, ln1b, x1f, x1b);

  // FFN
  gemm_bt<true,2><<<dim3(16, 64), blk, 0, stream>>>(x1b, W1, b1, hb, 8192, 2048, 1024);
  gemm_bt<true,1><<<dim3(8, 64), blk, 0, stream>>>(hb, W2, b2, fb2, 8192, 1024, 2048);

  // LN2(x1 + ff) -> out (f32)
  ln_kernel<1><<<8192, blk, 0, stream>>>(x1f, fb2, ln2w, ln2b, (float*)d_out, nullptr);
}

// Round 5
// 771.902 us; speedup vs baseline: 1.1998x; 1.1998x over previous
//
#include <hip/hip_runtime.h>
#include <stdint.h>
#include <math.h>

typedef unsigned short u16;
typedef __attribute__((ext_vector_type(8))) short s16x8;
typedef __attribute__((ext_vector_type(4))) short s16x4;
typedef __attribute__((ext_vector_type(4))) float f32x4;

__device__ __forceinline__ float bf2f(u16 v) {
  union { unsigned u; float f; } c; c.u = ((unsigned)v) << 16; return c.f;
}
__device__ __forceinline__ u16 f2bf(float f) {
  union { float f; unsigned u; } c; c.f = f;
  unsigned u = c.u;
  u += 0x7fffu + ((u >> 16) & 1u);   // round-to-nearest-even
  return (u16)(u >> 16);
}

#define GLD_LDS16(g, l) __builtin_amdgcn_global_load_lds( \
    (const __attribute__((address_space(1))) void*)(g),   \
    (__attribute__((address_space(3))) void*)(l), 16, 0, 0)

// ---------------------------------------------------------------------------
// f32 -> bf16 bulk convert. 8 elems/thread.
// ---------------------------------------------------------------------------
__global__ __launch_bounds__(256) void cvt_bf16(const float* __restrict__ src,
                                                u16* __restrict__ dst, int n)
{
  const int i = (blockIdx.x * 256 + threadIdx.x) * 8;
  if (i >= n) return;
  float4 a = *(const float4*)&src[i];
  float4 b = *(const float4*)&src[i + 4];
  s16x8 h;
  h[0] = (short)f2bf(a.x); h[1] = (short)f2bf(a.y);
  h[2] = (short)f2bf(a.z); h[3] = (short)f2bf(a.w);
  h[4] = (short)f2bf(b.x); h[5] = (short)f2bf(b.y);
  h[6] = (short)f2bf(b.z); h[7] = (short)f2bf(b.w);
  *(s16x8*)&dst[i] = h;
}

// ---------------------------------------------------------------------------
// GEMM: C[M,N] = A[M,K] * B[N,K]^T + bias[N]. A,B bf16 via global_load_lds.
// EPI: 0 = bf16, 1 = f32, 2 = mish->bf16,
//      3 = per-head RMSNorm * w * 0.125 -> bf16 (Q path, head = 64-col group)
//      4 = per-head RMSNorm * w -> bf16 (K path)
// For EPI 3/4 the 128-wide N-tile spans 2 heads; wave wc owns exactly one.
// ---------------------------------------------------------------------------
template<int EPI>
__global__ __launch_bounds__(256) void gemm_bb(
    const u16* __restrict__ A, const u16* __restrict__ B,
    const float* __restrict__ bias, const float* __restrict__ w,
    void* __restrict__ Cv, int M, int N, int K)
{
  __shared__ __align__(16) u16 As[128*32];
  __shared__ __align__(16) u16 Bs[128*32];
  const int tid = threadIdx.x;
  const int lane = tid & 63;
  const int wave = tid >> 6;
  const int wr = wave >> 1, wc = wave & 1;
  const int l15 = lane & 15, kg = lane >> 4;
  const long bm = (long)blockIdx.y * 128, bn = (long)blockIdx.x * 128;

  f32x4 acc[4][4] = {};

  for (int k0 = 0; k0 < K; k0 += 32) {
#pragma unroll
    for (int i = 0; i < 2; ++i) {
      const int e = (i*256 + tid) * 8;
      const int row = e >> 5, col = e & 31;
      GLD_LDS16(A + (bm + row) * (long)K + k0 + col, (char*)As + (i*4 + wave)*1024);
      GLD_LDS16(B + (bn + row) * (long)K + k0 + col, (char*)Bs + (i*4 + wave)*1024);
    }
    __syncthreads();
    s16x8 a[4], b[4];
#pragma unroll
    for (int mi = 0; mi < 4; ++mi)
      a[mi] = *(const s16x8*)&As[(wr*64 + mi*16 + l15)*32 + kg*8];
#pragma unroll
    for (int ni = 0; ni < 4; ++ni)
      b[ni] = *(const s16x8*)&Bs[(wc*64 + ni*16 + l15)*32 + kg*8];
#pragma unroll
    for (int mi = 0; mi < 4; ++mi)
#pragma unroll
      for (int ni = 0; ni < 4; ++ni)
        acc[mi][ni] = __builtin_amdgcn_mfma_f32_16x16x32_bf16(a[mi], b[ni], acc[mi][ni], 0, 0, 0);
    __syncthreads();
  }

  if (EPI <= 2) {
#pragma unroll
    for (int mi = 0; mi < 4; ++mi) {
#pragma unroll
      for (int ni = 0; ni < 4; ++ni) {
        const long col = bn + wc*64 + ni*16 + l15;
        const float bvv = bias[col];
#pragma unroll
        for (int r = 0; r < 4; ++r) {
          const long row = bm + wr*64 + mi*16 + kg*4 + r;
          float v = acc[mi][ni][r] + bvv;
          if (EPI == 0) {
            ((u16*)Cv)[row * N + col] = f2bf(v);
          } else if (EPI == 1) {
            ((float*)Cv)[row * N + col] = v;
          } else {
            float sp = (v > 20.f) ? v : log1pf(expf(v));
            ((u16*)Cv)[row * N + col] = f2bf(v * tanhf(sp));
          }
        }
      }
    }
  } else {
    // fused per-head RMSNorm: wave wc's 64 cols = one full head per row
#pragma unroll
    for (int mi = 0; mi < 4; ++mi) {
      float vv[4][4];
      float ssq[4] = {0.f, 0.f, 0.f, 0.f};
#pragma unroll
      for (int ni = 0; ni < 4; ++ni) {
        const long col = bn + wc*64 + ni*16 + l15;
        const float bvv = bias[col];
#pragma unroll
        for (int r = 0; r < 4; ++r) {
          const float vx = acc[mi][ni][r] + bvv;
          vv[ni][r] = vx;
          ssq[r] += vx * vx;
        }
      }
#pragma unroll
      for (int r = 0; r < 4; ++r) {
        ssq[r] += __shfl_xor(ssq[r], 1);
        ssq[r] += __shfl_xor(ssq[r], 2);
        ssq[r] += __shfl_xor(ssq[r], 4);
        ssq[r] += __shfl_xor(ssq[r], 8);
        float rr = rsqrtf(ssq[r] * (1.f/64.f) + 1e-6f);
        ssq[r] = (EPI == 3) ? rr * 0.125f : rr;
      }
#pragma unroll
      for (int ni = 0; ni < 4; ++ni) {
        const long col = bn + wc*64 + ni*16 + l15;
        const float wv_ = w[ni*16 + l15];
#pragma unroll
        for (int r = 0; r < 4; ++r) {
          const long row = bm + wr*64 + mi*16 + kg*4 + r;
          ((u16*)Cv)[row * N + col] = f2bf(vv[ni][r] * ssq[r] * wv_);
        }
      }
    }
  }
}

// ---------------------------------------------------------------------------
// Flash attention. Block = (q-tile 64, head, batch), 4 waves (16 q rows each).
// Q pre-scaled by 0.125 (folded into Q-GEMM epilogue). Bias read f32 direct
// to registers (no LDS). Q/K tiles staged via global_load_lds.
// ---------------------------------------------------------------------------
__global__ __launch_bounds__(256) void attn_kernel(
    const u16* __restrict__ q, const u16* __restrict__ k, const u16* __restrict__ v,
    const float* __restrict__ bias, u16* __restrict__ out)
{
  const int T = 1024, Dm = 1024, H = 16;
  const int q0 = blockIdx.x * 64;
  const int h  = blockIdx.y;
  const int b  = blockIdx.z;
  __shared__ __align__(16) u16 Qs[64*64];
  __shared__ __align__(16) u16 Ks[64*64];
  __shared__ __align__(16) u16 Vt[64*64];
  __shared__ __align__(16) u16 Ps[64*64];
  const int tid = threadIdx.x, lane = tid & 63, wave = tid >> 6;
  const int l15 = lane & 15, kg = lane >> 4;

  // stage Q tile via global_load_lds (already scaled+rms'd)
#pragma unroll
  for (int i = 0; i < 2; ++i) {
    const int e = (i*256 + tid) * 8;
    const int r = e >> 6, d0 = e & 63;
    GLD_LDS16(q + (size_t)(b*T + q0 + r) * Dm + h*64 + d0, (char*)Qs + (i*4 + wave)*1024);
  }

  f32x4 accO[4] = {};
  float m_i[4], l_i[4];
#pragma unroll
  for (int r = 0; r < 4; ++r) { m_i[r] = -1e30f; l_i[r] = 0.f; }

  const float* bp = bias + ((size_t)(b*H + h)*T + q0 + wave*16 + kg*4) * T;

  for (int kv0 = 0; kv0 < T; kv0 += 64) {
    __syncthreads();   // prev tile's LDS reads complete (also drains Q GLD)
#pragma unroll
    for (int i = 0; i < 2; ++i) {
      const int e = (i*256 + tid) * 8;
      const int r = e >> 6, d0 = e & 63;
      GLD_LDS16(k + (size_t)(b*T + kv0 + r) * Dm + h*64 + d0, (char*)Ks + (i*4 + wave)*1024);
      s16x8 v8 = *(const s16x8*)&v[(size_t)(b*T + kv0 + r) * Dm + h*64 + d0];
#pragma unroll
      for (int j = 0; j < 8; ++j) Vt[(d0 + j)*64 + r] = (u16)v8[j];
    }
    // bias direct to registers: rows kg*4+r of this wave, cols ni*16+l15
    float bl[4][4];
#pragma unroll
    for (int r = 0; r < 4; ++r)
#pragma unroll
      for (int ni = 0; ni < 4; ++ni)
        bl[r][ni] = bp[(size_t)r*T + kv0 + ni*16 + l15];
    __syncthreads();

    // S = Q K^T + bias
    f32x4 s[4] = {};
#pragma unroll
    for (int kc = 0; kc < 64; kc += 32) {
      s16x8 aq = *(const s16x8*)&Qs[(wave*16 + l15)*64 + kc + kg*8];
#pragma unroll
      for (int ni = 0; ni < 4; ++ni) {
        s16x8 bk = *(const s16x8*)&Ks[(ni*16 + l15)*64 + kc + kg*8];
        s[ni] = __builtin_amdgcn_mfma_f32_16x16x32_bf16(aq, bk, s[ni], 0, 0, 0);
      }
    }
    float pmax[4] = {-1e30f, -1e30f, -1e30f, -1e30f};
#pragma unroll
    for (int ni = 0; ni < 4; ++ni)
#pragma unroll
      for (int r = 0; r < 4; ++r) {
        const float sv = s[ni][r] + bl[r][ni];
        s[ni][r] = sv;
        pmax[r] = fmaxf(pmax[r], sv);
      }
#pragma unroll
    for (int r = 0; r < 4; ++r) {
#pragma unroll
      for (int off = 1; off < 16; off <<= 1)
        pmax[r] = fmaxf(pmax[r], __shfl_xor(pmax[r], off));
    }
    float alpha[4];
#pragma unroll
    for (int r = 0; r < 4; ++r) {
      const float mn = fmaxf(m_i[r], pmax[r]);
      alpha[r] = __expf(m_i[r] - mn);
      m_i[r] = mn;
    }
    float psum[4] = {0.f, 0.f, 0.f, 0.f};
#pragma unroll
    for (int ni = 0; ni < 4; ++ni)
#pragma unroll
      for (int r = 0; r < 4; ++r) {
        const float p = __expf(s[ni][r] - m_i[r]);
        psum[r] += p;
        Ps[(wave*16 + kg*4 + r)*64 + ni*16 + l15] = f2bf(p);
      }
#pragma unroll
    for (int r = 0; r < 4; ++r) {
#pragma unroll
      for (int off = 1; off < 16; off <<= 1)
        psum[r] += __shfl_xor(psum[r], off);
      l_i[r] = l_i[r] * alpha[r] + psum[r];
    }
#pragma unroll
    for (int nd = 0; nd < 4; ++nd)
#pragma unroll
      for (int r = 0; r < 4; ++r)
        accO[nd][r] *= alpha[r];
    // O += P V   (Ps rows are wave-local; Vt: [d][kv])
#pragma unroll
    for (int kc = 0; kc < 64; kc += 32) {
      s16x8 ap = *(const s16x8*)&Ps[(wave*16 + l15)*64 + kc + kg*8];
#pragma unroll
      for (int nd = 0; nd < 4; ++nd) {
        s16x8 bv = *(const s16x8*)&Vt[(nd*16 + l15)*64 + kc + kg*8];
        accO[nd] = __builtin_amdgcn_mfma_f32_16x16x32_bf16(ap, bv, accO[nd], 0, 0, 0);
      }
    }
  }

#pragma unroll
  for (int nd = 0; nd < 4; ++nd)
#pragma unroll
    for (int r = 0; r < 4; ++r) {
      const int row = q0 + wave*16 + kg*4 + r;
      const int col = h*64 + nd*16 + l15;
      out[(size_t)(b*T + row) * Dm + col] = f2bf(accO[nd][r] / l_i[r]);
    }
}

// ---------------------------------------------------------------------------
// LayerNorm(xa_f32 + xb_f32) * w + b.  One block per row, D=1024.
// MODE 0: write f32 outf AND bf16 outb.  MODE 1: write f32 outf only.
// ---------------------------------------------------------------------------
template<int MODE>
__global__ __launch_bounds__(256) void ln_kernel(
    const float* __restrict__ xa, const float* __restrict__ xb,
    const float* __restrict__ w, const float* __restrict__ bvec,
    float* __restrict__ outf, u16* __restrict__ outb)
{
  __shared__ float red[2][4];
  const int row = blockIdx.x;
  const int tid = threadIdx.x;
  const long base = (long)row * 1024 + tid*4;

  float4 xv = *(const float4*)&xa[base];
  float4 bv4 = *(const float4*)&xb[base];
  float vals[4];
  vals[0] = xv.x + bv4.x;
  vals[1] = xv.y + bv4.y;
  vals[2] = xv.z + bv4.z;
  vals[3] = xv.w + bv4.w;
  float s = 0.f, sq = 0.f;
#pragma unroll
  for (int j = 0; j < 4; ++j) { s += vals[j]; sq += vals[j]*vals[j]; }
#pragma unroll
  for (int off = 32; off; off >>= 1) {
    s  += __shfl_xor(s, off);
    sq += __shfl_xor(sq, off);
  }
  const int wv = tid >> 6;
  if ((tid & 63) == 0) { red[0][wv] = s; red[1][wv] = sq; }
  __syncthreads();
  const float st  = red[0][0] + red[0][1] + red[0][2] + red[0][3];
  const float sqt = red[1][0] + red[1][1] + red[1][2] + red[1][3];
  const float mu  = st * (1.f/1024.f);
  const float var = sqt * (1.f/1024.f) - mu*mu;
  const float rstd = rsqrtf(var + 1e-5f);
  float4 of;
  of.x = (vals[0] - mu) * rstd * w[tid*4+0] + bvec[tid*4+0];
  of.y = (vals[1] - mu) * rstd * w[tid*4+1] + bvec[tid*4+1];
  of.z = (vals[2] - mu) * rstd * w[tid*4+2] + bvec[tid*4+2];
  of.w = (vals[3] - mu) * rstd * w[tid*4+3] + bvec[tid*4+3];
  *(float4*)&outf[base] = of;
  if (MODE == 0) {
    s16x4 hb4;
    hb4[0] = (short)f2bf(of.x); hb4[1] = (short)f2bf(of.y);
    hb4[2] = (short)f2bf(of.z); hb4[3] = (short)f2bf(of.w);
    *(s16x4*)&outb[base] = hb4;
  }
}

// ---------------------------------------------------------------------------
extern "C" void kernel_launch(void* const* d_in, const int* in_sizes, int n_in,
                              void* d_out, int out_size, void* d_ws, size_t ws_size,
                              hipStream_t stream)
{
  (void)in_sizes; (void)n_in; (void)out_size; (void)ws_size;
  const float* x    = (const float*)d_in[0];
  const float* sg   = (const float*)d_in[1];
  const float* Wq   = (const float*)d_in[2];
  const float* bq   = (const float*)d_in[3];
  const float* Wk   = (const float*)d_in[4];
  const float* bk   = (const float*)d_in[5];
  const float* Wv   = (const float*)d_in[6];
  const float* bv   = (const float*)d_in[7];
  const float* Wo   = (const float*)d_in[8];
  const float* bo   = (const float*)d_in[9];
  const float* qn   = (const float*)d_in[10];
  const float* kn   = (const float*)d_in[11];
  const float* ln1w = (const float*)d_in[12];
  const float* ln1b = (const float*)d_in[13];
  const float* W1   = (const float*)d_in[14];
  const float* b1   = (const float*)d_in[15];
  const float* W2   = (const float*)d_in[16];
  const float* b2   = (const float*)d_in[17];
  const float* ln2w = (const float*)d_in[18];
  const float* ln2b = (const float*)d_in[19];

  char* ws = (char*)d_ws;
  // liveness-planned layout, high water 128 MB (144 MB proven safe in R4)
  u16*   xb  = (u16*)(ws + (0ll   << 20));  // 16 MB  x bf16 (dead after QKV)
  u16*   wqb = (u16*)(ws + (16ll  << 20));  //  2 MB
  u16*   wkb = (u16*)(ws + (18ll  << 20));  //  2 MB
  u16*   wvb = (u16*)(ws + (20ll  << 20));  //  2 MB
  u16*   wob = (u16*)(ws + (22ll  << 20));  //  2 MB
  u16*   w1b = (u16*)(ws + (24ll  << 20));  //  4 MB
  u16*   w2b = (u16*)(ws + (28ll  << 20));  //  4 MB
  u16*   qb  = (u16*)(ws + (32ll  << 20));  // 16 MB (dead after attn)
  u16*   kb  = (u16*)(ws + (48ll  << 20));  // 16 MB (dead after attn)
  u16*   vb  = (u16*)(ws + (64ll  << 20));  // 16 MB (dead after attn)
  u16*   ao  = (u16*)(ws + (0ll   << 20));  // 16 MB reuse xb (dead after proj)
  float* fb  = (float*)(ws + (32ll << 20)); // 32 MB f32 reuse qb+kb (dead after LN1)
  float* x1f = (float*)(ws + (64ll << 20)); // 32 MB f32 reuse vb+fresh (live to LN2)
  u16*   x1b = (u16*)(ws + (0ll   << 20));  // 16 MB reuse ao (dead after FFN1)
  u16*   hb  = (u16*)(ws + (32ll  << 20));  // 32 MB reuse fb (dead after FFN2)
  float* fb2 = (float*)(ws + (96ll << 20)); // 32 MB f32 fresh

  const dim3 blk(256);

  // ---- stage 0: bulk f32->bf16 conversions (one-time per launch)
  cvt_bf16<<<4096, blk, 0, stream>>>(x,  xb,  8388608);
  cvt_bf16<<<512,  blk, 0, stream>>>(Wq, wqb, 1048576);
  cvt_bf16<<<512,  blk, 0, stream>>>(Wk, wkb, 1048576);
  cvt_bf16<<<512,  blk, 0, stream>>>(Wv, wvb, 1048576);
  cvt_bf16<<<512,  blk, 0, stream>>>(Wo, wob, 1048576);
  cvt_bf16<<<1024, blk, 0, stream>>>(W1, w1b, 2097152);
  cvt_bf16<<<1024, blk, 0, stream>>>(W2, w2b, 2097152);

  // ---- QKV projections with fused per-head RMSNorm (Q also *0.125)
  gemm_bb<3><<<dim3(8, 64), blk, 0, stream>>>(xb, wqb, bq, qn, qb, 8192, 1024, 1024);
  gemm_bb<4><<<dim3(8, 64), blk, 0, stream>>>(xb, wkb, bk, kn, kb, 8192, 1024, 1024);
  gemm_bb<0><<<dim3(8, 64), blk, 0, stream>>>(xb, wvb, bv, nullptr, vb, 8192, 1024, 1024);

  // ---- attention with smolgen bias (f32 direct)
  attn_kernel<<<dim3(16, 16, 8), blk, 0, stream>>>(qb, kb, vb, sg, ao);

  // ---- output projection -> f32
  gemm_bb<1><<<dim3(8, 64), blk, 0, stream>>>(ao, wob, bo, nullptr, fb, 8192, 1024, 1024);

  // ---- LN1(x + proj) -> x1f (f32) + x1b (bf16)
  ln_kernel<0><<<8192, blk, 0, stream>>>(x, fb, ln1w, ln1b, x1f, x1b);

  // ---- FFN
  gemm_bb<2><<<dim3(16, 64), blk, 0, stream>>>(x1b, w1b, b1, nullptr, hb, 8192, 2048, 1024);
  gemm_bb<1><<<dim3(8, 64), blk, 0, stream>>>(hb, w2b, b2, nullptr, fb2, 8192, 1024, 2048);

  // ---- LN2(x1 + ff) -> out (f32)
  ln_kernel<1><<<8192, blk, 0, stream>>>(x1f, fb2, ln2w, ln2b, (float*)d_out, nullptr);
}